// Round 20
// baseline (86.956 us; speedup 1.0000x reference)
//
#include <hip/hip_runtime.h>
#include <hip/hip_bf16.h>
#include <math.h>

// Problem constants
#define B_ 512
#define L_ 256
#define D_ 256
#define V_ 100000
#define O_ 1000

typedef __attribute__((ext_vector_type(8))) short short8;
typedef __attribute__((ext_vector_type(4))) float f32x4;

static __device__ __forceinline__ unsigned short f2bf(float f) {
    union { float f; unsigned u; } v; v.f = f;
    unsigned r = v.u + 0x7FFFu + ((v.u >> 16) & 1u);   // RNE (inputs are finite)
    return (unsigned short)(r >> 16);
}
static __device__ __forceinline__ float bf2f(unsigned short u) {
    union { unsigned u; float f; } v; v.u = ((unsigned)u) << 16;
    return v.f;
}
static __device__ __forceinline__ short8 pack8(float4 a, float4 c) {
    short8 o;
    o[0] = (short)f2bf(a.x); o[1] = (short)f2bf(a.y);
    o[2] = (short)f2bf(a.z); o[3] = (short)f2bf(a.w);
    o[4] = (short)f2bf(c.x); o[5] = (short)f2bf(c.y);
    o[6] = (short)f2bf(c.z); o[7] = (short)f2bf(c.w);
    return o;
}
// fred bank-spread swizzle (valid as fsw(base)+j, j<4, base%4==0)
static __device__ __forceinline__ int fsw(int d) { return d ^ (((d >> 5) & 7) << 2); }

// ---------------- Kernel 1: W_b cast to bf16 (row-major) ----------------
// Separate tiny dispatch (r17/r18: in-kernel conversion triggers wfr/efr spill).
__global__ __launch_bounds__(256) void k_wt(const float* __restrict__ Wb,
                                            unsigned short* __restrict__ Wbf) {
    int i = blockIdx.x * 256 + threadIdx.x;       // 65536
    Wbf[i] = f2bf(Wb[i]);
}

// ---------------- Kernel 2 (fused): per-batch gather + G = E_b*W_b*E_b^T + softmax + f_w ----
// One block per batch, 512 threads (8 waves), 1 block/CU (160KB LDS).
// == r19/r16 core (proven 64.6us, clean) + ONE delta: full-depth gather pipeline ==
// ALL rows 64-255 issued as 12 float4-pairs after barrier A, landed after P1(0).
// r19's serial tail (rows 160-255 before barrier B) exposed ~2us/block of L3/HBM
// latency; now it hides under P1(0). (b)-alone is untested: r17/r18's spill trigger
// was the in-kernel Wb convert (a), not this batch — 124+48=172 VGPR < 256 cap.
// Es/Ht swizzle: row r, 16B-aligned byte col c at (r<<9) | (c ^ ((r&15)<<4)).
// tanh(max)=max(tanh) -> softmax over L -> f_w = a^T E (from Es; fred bank-swizzled).
__global__ __launch_bounds__(512, 2) void k_attn(const int* __restrict__ tok,
                                                 const float* __restrict__ emb,
                                                 const unsigned short* __restrict__ Wbf,
                                                 float* __restrict__ fw) {
    __shared__ __align__(16) char lds[163840];
    char* EsC = lds;                                   // 128KB: swizzled E_b
    char* HtC = lds + 131072;                          // 32KB: Ht tile (64 rows x 512B, swizzled)
    float* red2    = (float*)(lds + 131072);           // overlay: 256 f32
    float* scratch = (float*)(lds + 132096);           // overlay: 16 f32
    float* fred    = (float*)(lds + 132160);           // overlay: 16 x 256 f32

    int b = blockIdx.x;
    int tid = threadIdx.x;
    int wid = tid >> 6, ln = tid & 63;
    int l16 = ln & 15, gp = ln >> 4;
    int i0 = wid * 32;          // wave's Wb-row block (P1) / G-row block (P2)
    const int* tb = tok + (b << 8);

    // ---- Wb A-frag preload (global, L2-hot): rows [i0, i0+32) -> 64 VGPR ----
    short8 wfr[8][2];
#pragma unroll
    for (int k = 0; k < 8; k++)
#pragma unroll
        for (int rf = 0; rf < 2; rf++)
            wfr[k][rf] = *(const short8*)(Wbf + ((i0 + rf * 16 + l16) << 8) + k * 32 + gp * 8);

    // ---- gather chunk 0 (rows 0..63): it 0..3 ----
#pragma unroll
    for (int it = 0; it < 4; it++) {
        int c = it * 512 + tid;
        int row = c >> 5, c16 = c & 31;
        const float4* src = (const float4*)(emb + ((size_t)tb[row] << 8) + (c16 << 3));
        short8 o = pack8(src[0], src[1]);
        *(short8*)(EsC + ((row << 9) | ((c16 << 4) ^ ((row & 15) << 4)))) = o;
    }
    __syncthreads();   // barrier A: rows 0-63 visible

    // ---- issue loads for ALL rows 64..255 (12 pairs); land them AFTER P1(0) ----
    float4 ga[12], gb[12];
#pragma unroll
    for (int it = 0; it < 12; it++) {
        int c = (it + 4) * 512 + tid;
        int row = c >> 5, c16 = c & 31;
        const float4* src = (const float4*)(emb + ((size_t)tb[row] << 8) + (c16 << 3));
        ga[it] = src[0]; gb[it] = src[1];
    }

    float rmax[8];
#pragma unroll
    for (int i = 0; i < 8; i++) rmax[i] = -1e30f;

    // ---- phase 1 / phase 2 bodies ----
    auto P1 = [&](int m0) {
        f32x4 acc[2][4] = {};
#pragma unroll
        for (int k0 = 0; k0 < 256; k0 += 32) {
            int kk2 = (k0 + gp * 8) * 2;
            short8 bfr[4];
#pragma unroll
            for (int cf = 0; cf < 4; cf++) {
                int jg = m0 + cf * 16 + l16;
                bfr[cf] = *(const short8*)(EsC + ((jg << 9) | (kk2 ^ ((jg & 15) << 4))));
            }
            int ks = k0 >> 5;
            __builtin_amdgcn_s_setprio(1);
#pragma unroll
            for (int rf = 0; rf < 2; rf++)
#pragma unroll
                for (int cf = 0; cf < 4; cf++)
                    acc[rf][cf] = __builtin_amdgcn_mfma_f32_16x16x32_bf16(
                        wfr[ks][rf], bfr[cf], acc[rf][cf], 0, 0, 0);
            __builtin_amdgcn_s_setprio(0);
        }
        // store transposed: H'[i][j] -> Ht[j-m0][i], 8B packs, swizzled
#pragma unroll
        for (int rf = 0; rf < 2; rf++)
#pragma unroll
            for (int cf = 0; cf < 4; cf++) {
                int i = i0 + rf * 16 + gp * 4;
                int jl = cf * 16 + l16;
                unsigned long long pk;
                unsigned short* p = (unsigned short*)&pk;
                p[0] = f2bf(acc[rf][cf][0]);
                p[1] = f2bf(acc[rf][cf][1]);
                p[2] = f2bf(acc[rf][cf][2]);
                p[3] = f2bf(acc[rf][cf][3]);
                *(unsigned long long*)(HtC + ((jl << 9) | ((i * 2) ^ ((jl & 15) << 4)))) = pk;
            }
    };

    short8 efr[8][2];
    auto P2 = [&]() {
        f32x4 acc[2][4] = {};
#pragma unroll
        for (int k0 = 0; k0 < 256; k0 += 32) {
            int kk2 = (k0 + gp * 8) * 2;
            short8 bb[4];
#pragma unroll
            for (int cf = 0; cf < 4; cf++) {
                int m = cf * 16 + l16;
                bb[cf] = *(const short8*)(HtC + ((m << 9) | (kk2 ^ ((m & 15) << 4))));
            }
            int ks = k0 >> 5;
            __builtin_amdgcn_s_setprio(1);
#pragma unroll
            for (int rf = 0; rf < 2; rf++)
#pragma unroll
                for (int cf = 0; cf < 4; cf++)
                    acc[rf][cf] = __builtin_amdgcn_mfma_f32_16x16x32_bf16(
                        efr[ks][rf], bb[cf], acc[rf][cf], 0, 0, 0);
            __builtin_amdgcn_s_setprio(0);
        }
#pragma unroll
        for (int rf = 0; rf < 2; rf++)
#pragma unroll
            for (int r = 0; r < 4; r++) {
                float mx = fmaxf(fmaxf(acc[rf][0][r], acc[rf][1][r]),
                                 fmaxf(acc[rf][2][r], acc[rf][3][r]));
                rmax[rf * 4 + r] = fmaxf(rmax[rf * 4 + r], mx);
            }
    };

    // ---- P1(0) runs while rows 64-255 are in flight ----
    P1(0);

    // land rows 64..255 (disjoint from rows 0-63 P1 reads; no barrier needed)
#pragma unroll
    for (int it = 0; it < 12; it++) {
        int c = (it + 4) * 512 + tid;
        int row = c >> 5, c16 = c & 31;
        short8 o = pack8(ga[it], gb[it]);
        *(short8*)(EsC + ((row << 9) | ((c16 << 4) ^ ((row & 15) << 4)))) = o;
    }
    __syncthreads();   // barrier B: all E rows + Ht(0) visible

    // ---- E A-frag preload (from LDS): rows [i0, i0+32) -> 64 VGPR ----
#pragma unroll
    for (int k = 0; k < 8; k++)
#pragma unroll
        for (int rf = 0; rf < 2; rf++) {
            int l = i0 + rf * 16 + l16;
            efr[k][rf] = *(const short8*)(EsC + ((l << 9) | ((k * 64 + gp * 16) ^ ((l & 15) << 4))));
        }

    P2();              // mt = 0
    __syncthreads();

    for (int mt = 1; mt < 4; mt++) {
        P1(mt * 64);
        __syncthreads();
        P2();
        __syncthreads();
    }

    // ---- reduce rowmax across l16 lanes, publish to red2 ----
#pragma unroll
    for (int i = 0; i < 8; i++) {
        float v = rmax[i];
        v = fmaxf(v, __shfl_xor(v, 1));
        v = fmaxf(v, __shfl_xor(v, 2));
        v = fmaxf(v, __shfl_xor(v, 4));
        v = fmaxf(v, __shfl_xor(v, 8));
        rmax[i] = v;
    }
    if (l16 == 0) {
#pragma unroll
        for (int rf = 0; rf < 2; rf++)
#pragma unroll
            for (int r = 0; r < 4; r++)
                red2[i0 + rf * 16 + gp * 4 + r] = rmax[rf * 4 + r];
    }
    __syncthreads();

    // ---- tanh + softmax over the 256 row-maxima ----
    float x = -1e30f;
    if (tid < 256) x = tanhf(red2[tid]);
    float mx = x;
#pragma unroll
    for (int s = 1; s < 64; s <<= 1) mx = fmaxf(mx, __shfl_xor(mx, s));
    if (ln == 0) scratch[wid] = mx;
    __syncthreads();
    float bm = scratch[0];
#pragma unroll
    for (int i = 1; i < 8; i++) bm = fmaxf(bm, scratch[i]);
    float e = (tid < 256) ? expf(x - bm) : 0.f;
    float sm = e;
#pragma unroll
    for (int s = 1; s < 64; s <<= 1) sm += __shfl_xor(sm, s);
    if (ln == 0) scratch[8 + wid] = sm;
    __syncthreads();
    float tot = 0.f;
#pragma unroll
    for (int i = 0; i < 8; i++) tot += scratch[8 + i];
    if (tid < 256) red2[tid] = e / tot;    // aq
    __syncthreads();

    // ---- f_w[d] = sum_l aq[l] * E_b[l][d]  (E from LDS, partials in fred, bank-swizzled) ----
    {
        int g = tid >> 5;                    // 0..15 -> l-range [16g, 16g+16)
        int d0 = (tid & 31) << 3;            // 8 d's per thread
        float s0[8] = {0.f, 0.f, 0.f, 0.f, 0.f, 0.f, 0.f, 0.f};
        int lbase = g << 4;
#pragma unroll
        for (int li = 0; li < 16; li++) {
            int l = lbase + li;
            float aql = red2[l];
            int byt = (l << 9) | ((d0 * 2) ^ ((l & 15) << 4));
            short8 v = *(const short8*)(EsC + byt);
#pragma unroll
            for (int jj = 0; jj < 8; jj++)
                s0[jj] += aql * bf2f((unsigned short)v[jj]);
        }
        f32x4 w0, w1;
        w0[0] = s0[0]; w0[1] = s0[1]; w0[2] = s0[2]; w0[3] = s0[3];
        w1[0] = s0[4]; w1[1] = s0[5]; w1[2] = s0[6]; w1[3] = s0[7];
        *(f32x4*)(fred + g * 256 + fsw(d0)) = w0;
        *(f32x4*)(fred + g * 256 + fsw(d0 + 4)) = w1;
    }
    __syncthreads();
    if (tid < 256) {
        float f = 0.f;
        int dw = fsw(tid);
#pragma unroll
        for (int g2 = 0; g2 < 16; g2++) f += fred[g2 * 256 + dw];
        fw[(b << 8) + tid] = f;
    }
}

// ---------------- Kernel 3: out = f_w @ lin_w^T + lin_b ----------------
// Single-stage LDS (1 barrier): BsT[k][n] transposed (float4 n-reads), As[m][k].
// Tile 32(M)x64(N), 256 blocks.  (r14-r19 proven: ~1us)
__global__ __launch_bounds__(256) void k_out(const float* __restrict__ fw,
                                             const float* __restrict__ lw,
                                             const float* __restrict__ lb,
                                             float* __restrict__ out) {
    __shared__ float BsT[256][68];   // [k][n]
    __shared__ float As[32][260];    // [m][k]
    int tid = threadIdx.x;
    int tx = tid & 15, ty = tid >> 4;
    int r0 = blockIdx.y * 32, n0 = blockIdx.x * 64;
#pragma unroll
    for (int it = 0; it < 8; it++) {
        int f4 = it * 256 + tid;
        int i = f4 >> 6, kc = (f4 & 63) << 2;
        *(float4*)&As[i][kc] = *(const float4*)&fw[(r0 + i) * 256 + kc];
    }
#pragma unroll
    for (int it = 0; it < 16; it++) {
        int f4 = it * 256 + tid;
        int n = f4 >> 6, kc = (f4 & 63) << 2;
        int nn = n0 + n;
        float4 v = {0.f, 0.f, 0.f, 0.f};
        if (nn < O_) v = *(const float4*)&lw[(size_t)nn * 256 + kc];
        BsT[kc][n] = v.x; BsT[kc + 1][n] = v.y; BsT[kc + 2][n] = v.z; BsT[kc + 3][n] = v.w;
    }
    __syncthreads();
    float acc[2][4] = {};
#pragma unroll 4
    for (int k = 0; k < 256; k++) {
        float4 bv = *(const float4*)&BsT[k][tx * 4];
        float a0 = As[ty * 2][k], a1 = As[ty * 2 + 1][k];
        acc[0][0] += a0 * bv.x; acc[0][1] += a0 * bv.y; acc[0][2] += a0 * bv.z; acc[0][3] += a0 * bv.w;
        acc[1][0] += a1 * bv.x; acc[1][1] += a1 * bv.y; acc[1][2] += a1 * bv.z; acc[1][3] += a1 * bv.w;
    }
#pragma unroll
    for (int i = 0; i < 2; i++)
#pragma unroll
        for (int j = 0; j < 4; j++) {
            int n = n0 + tx * 4 + j;
            if (n < O_) out[(size_t)(r0 + ty * 2 + i) * O_ + n] = acc[i][j] + lb[n];
        }
}

extern "C" void kernel_launch(void* const* d_in, const int* in_sizes, int n_in,
                              void* d_out, int out_size, void* d_ws, size_t ws_size,
                              hipStream_t stream) {
    const int* tok = (const int*)d_in[0];
    const float* emb = (const float*)d_in[1];
    const float* Wb = (const float*)d_in[2];
    const float* lw = (const float*)d_in[3];
    const float* lb = (const float*)d_in[4];
    float* out = (float*)d_out;

    char* ws = (char*)d_ws;
    unsigned short* Wbf = (unsigned short*)(ws);            // 131,072 B
    float*          fwp = (float*)(ws + 131072);            // 524,288 B

    hipLaunchKernelGGL(k_wt,   dim3(256),    dim3(256), 0, stream, Wb, Wbf);
    hipLaunchKernelGGL(k_attn, dim3(512),    dim3(512), 0, stream, tok, emb, Wbf, fwp);
    hipLaunchKernelGGL(k_out,  dim3(16, 16), dim3(256), 0, stream, fwp, lw, lb, out);
}

// Round 21
// 72.579 us; speedup vs baseline: 1.1981x; 1.1981x over previous
//
#include <hip/hip_runtime.h>
#include <hip/hip_bf16.h>
#include <math.h>

// Problem constants
#define B_ 512
#define L_ 256
#define D_ 256
#define V_ 100000
#define O_ 1000

typedef __attribute__((ext_vector_type(8))) short short8;
typedef __attribute__((ext_vector_type(4))) float f32x4;

static __device__ __forceinline__ unsigned short f2bf(float f) {
    union { float f; unsigned u; } v; v.f = f;
    unsigned r = v.u + 0x7FFFu + ((v.u >> 16) & 1u);   // RNE (inputs are finite)
    return (unsigned short)(r >> 16);
}
static __device__ __forceinline__ float bf2f(unsigned short u) {
    union { unsigned u; float f; } v; v.u = ((unsigned)u) << 16;
    return v.f;
}
static __device__ __forceinline__ short8 pack8(float4 a, float4 c) {
    short8 o;
    o[0] = (short)f2bf(a.x); o[1] = (short)f2bf(a.y);
    o[2] = (short)f2bf(a.z); o[3] = (short)f2bf(a.w);
    o[4] = (short)f2bf(c.x); o[5] = (short)f2bf(c.y);
    o[6] = (short)f2bf(c.z); o[7] = (short)f2bf(c.w);
    return o;
}
// fred bank-spread swizzle (valid as fsw(base)+j, j<4, base%4==0)
static __device__ __forceinline__ int fsw(int d) { return d ^ (((d >> 5) & 7) << 2); }

// ---------------- Kernel 1: W_b cast to bf16 (row-major) ----------------
// Separate tiny dispatch: in-kernel conversion spills wfr/efr (r17/r18);
// deep gather prefetch also spills (r20). This 3-dispatch split is the optimum.
__global__ __launch_bounds__(256) void k_wt(const float* __restrict__ Wb,
                                            unsigned short* __restrict__ Wbf) {
    int i = blockIdx.x * 256 + threadIdx.x;       // 65536
    Wbf[i] = f2bf(Wb[i]);
}

// ---------------- Kernel 2 (fused): per-batch gather + G = E_b*W_b*E_b^T + softmax + f_w ----
// One block per batch, 512 threads (8 waves), 1 block/CU (160KB LDS).
// == r16/r19 verbatim — twice-reproduced optimum (72.6us total, clean counters) ==
// r9 schedule + 4-bit swizzle (conflicts 5.0M -> 0.52M) + single-stage k_out.
// Es/Ht swizzle: row r, 16B-aligned byte col c at (r<<9) | (c ^ ((r&15)<<4)).
// Core: full E_b in LDS (128KB), wfr regs (32 Wb rows/wave), efr regs (32 E rows/wave),
// mt-loop {P1 -> Ht 32KB; barrier; P2 rowmax; barrier}; 6-pair split-gather overlap
// (12-pair spills, r20); setprio around MFMA clusters; fred store bank-swizzled.
// tanh(max)=max(tanh) -> softmax over L -> f_w = a^T E (from Es).
__global__ __launch_bounds__(512, 2) void k_attn(const int* __restrict__ tok,
                                                 const float* __restrict__ emb,
                                                 const unsigned short* __restrict__ Wbf,
                                                 float* __restrict__ fw) {
    __shared__ __align__(16) char lds[163840];
    char* EsC = lds;                                   // 128KB: swizzled E_b
    char* HtC = lds + 131072;                          // 32KB: Ht tile (64 rows x 512B, swizzled)
    float* red2    = (float*)(lds + 131072);           // overlay: 256 f32
    float* scratch = (float*)(lds + 132096);           // overlay: 16 f32
    float* fred    = (float*)(lds + 132160);           // overlay: 16 x 256 f32

    int b = blockIdx.x;
    int tid = threadIdx.x;
    int wid = tid >> 6, ln = tid & 63;
    int l16 = ln & 15, gp = ln >> 4;
    int i0 = wid * 32;          // wave's Wb-row block (P1) / G-row block (P2)
    const int* tb = tok + (b << 8);

    // ---- Wb A-frag preload (global, L2-hot): rows [i0, i0+32) -> 64 VGPR ----
    short8 wfr[8][2];
#pragma unroll
    for (int k = 0; k < 8; k++)
#pragma unroll
        for (int rf = 0; rf < 2; rf++)
            wfr[k][rf] = *(const short8*)(Wbf + ((i0 + rf * 16 + l16) << 8) + k * 32 + gp * 8);

    // ---- gather chunk 0 (rows 0..63): it 0..3 ----
#pragma unroll
    for (int it = 0; it < 4; it++) {
        int c = it * 512 + tid;
        int row = c >> 5, c16 = c & 31;
        const float4* src = (const float4*)(emb + ((size_t)tb[row] << 8) + (c16 << 3));
        short8 o = pack8(src[0], src[1]);
        *(short8*)(EsC + ((row << 9) | ((c16 << 4) ^ ((row & 15) << 4)))) = o;
    }
    __syncthreads();   // barrier A: rows 0-63 visible

    // ---- issue loads for rows 64..159 (it 4..9) into regs; land them AFTER P1(0) ----
    float4 ga[6], gb[6];
#pragma unroll
    for (int it = 0; it < 6; it++) {
        int c = (it + 4) * 512 + tid;
        int row = c >> 5, c16 = c & 31;
        const float4* src = (const float4*)(emb + ((size_t)tb[row] << 8) + (c16 << 3));
        ga[it] = src[0]; gb[it] = src[1];
    }

    float rmax[8];
#pragma unroll
    for (int i = 0; i < 8; i++) rmax[i] = -1e30f;

    // ---- phase 1 / phase 2 bodies ----
    auto P1 = [&](int m0) {
        f32x4 acc[2][4] = {};
#pragma unroll
        for (int k0 = 0; k0 < 256; k0 += 32) {
            int kk2 = (k0 + gp * 8) * 2;
            short8 bfr[4];
#pragma unroll
            for (int cf = 0; cf < 4; cf++) {
                int jg = m0 + cf * 16 + l16;
                bfr[cf] = *(const short8*)(EsC + ((jg << 9) | (kk2 ^ ((jg & 15) << 4))));
            }
            int ks = k0 >> 5;
            __builtin_amdgcn_s_setprio(1);
#pragma unroll
            for (int rf = 0; rf < 2; rf++)
#pragma unroll
                for (int cf = 0; cf < 4; cf++)
                    acc[rf][cf] = __builtin_amdgcn_mfma_f32_16x16x32_bf16(
                        wfr[ks][rf], bfr[cf], acc[rf][cf], 0, 0, 0);
            __builtin_amdgcn_s_setprio(0);
        }
        // store transposed: H'[i][j] -> Ht[j-m0][i], 8B packs, swizzled
#pragma unroll
        for (int rf = 0; rf < 2; rf++)
#pragma unroll
            for (int cf = 0; cf < 4; cf++) {
                int i = i0 + rf * 16 + gp * 4;
                int jl = cf * 16 + l16;
                unsigned long long pk;
                unsigned short* p = (unsigned short*)&pk;
                p[0] = f2bf(acc[rf][cf][0]);
                p[1] = f2bf(acc[rf][cf][1]);
                p[2] = f2bf(acc[rf][cf][2]);
                p[3] = f2bf(acc[rf][cf][3]);
                *(unsigned long long*)(HtC + ((jl << 9) | ((i * 2) ^ ((jl & 15) << 4)))) = pk;
            }
    };

    short8 efr[8][2];
    auto P2 = [&]() {
        f32x4 acc[2][4] = {};
#pragma unroll
        for (int k0 = 0; k0 < 256; k0 += 32) {
            int kk2 = (k0 + gp * 8) * 2;
            short8 bb[4];
#pragma unroll
            for (int cf = 0; cf < 4; cf++) {
                int m = cf * 16 + l16;
                bb[cf] = *(const short8*)(HtC + ((m << 9) | (kk2 ^ ((m & 15) << 4))));
            }
            int ks = k0 >> 5;
            __builtin_amdgcn_s_setprio(1);
#pragma unroll
            for (int rf = 0; rf < 2; rf++)
#pragma unroll
                for (int cf = 0; cf < 4; cf++)
                    acc[rf][cf] = __builtin_amdgcn_mfma_f32_16x16x32_bf16(
                        efr[ks][rf], bb[cf], acc[rf][cf], 0, 0, 0);
            __builtin_amdgcn_s_setprio(0);
        }
#pragma unroll
        for (int rf = 0; rf < 2; rf++)
#pragma unroll
            for (int r = 0; r < 4; r++) {
                float mx = fmaxf(fmaxf(acc[rf][0][r], acc[rf][1][r]),
                                 fmaxf(acc[rf][2][r], acc[rf][3][r]));
                rmax[rf * 4 + r] = fmaxf(rmax[rf * 4 + r], mx);
            }
    };

    // ---- P1(0) runs while rows 64-159 are in flight ----
    P1(0);

    // land rows 64..159 (disjoint from rows 0-63 P1 reads; no barrier needed)
#pragma unroll
    for (int it = 0; it < 6; it++) {
        int c = (it + 4) * 512 + tid;
        int row = c >> 5, c16 = c & 31;
        short8 o = pack8(ga[it], gb[it]);
        *(short8*)(EsC + ((row << 9) | ((c16 << 4) ^ ((row & 15) << 4)))) = o;
    }
    // gather rows 160..255 (it 10..15)
#pragma unroll
    for (int it = 10; it < 16; it++) {
        int c = it * 512 + tid;
        int row = c >> 5, c16 = c & 31;
        const float4* src = (const float4*)(emb + ((size_t)tb[row] << 8) + (c16 << 3));
        short8 o = pack8(src[0], src[1]);
        *(short8*)(EsC + ((row << 9) | ((c16 << 4) ^ ((row & 15) << 4)))) = o;
    }
    __syncthreads();   // barrier B: all E rows + Ht(0) visible

    // ---- E A-frag preload (from LDS): rows [i0, i0+32) -> 64 VGPR ----
#pragma unroll
    for (int k = 0; k < 8; k++)
#pragma unroll
        for (int rf = 0; rf < 2; rf++) {
            int l = i0 + rf * 16 + l16;
            efr[k][rf] = *(const short8*)(EsC + ((l << 9) | ((k * 64 + gp * 16) ^ ((l & 15) << 4))));
        }

    P2();              // mt = 0
    __syncthreads();

    for (int mt = 1; mt < 4; mt++) {
        P1(mt * 64);
        __syncthreads();
        P2();
        __syncthreads();
    }

    // ---- reduce rowmax across l16 lanes, publish to red2 ----
#pragma unroll
    for (int i = 0; i < 8; i++) {
        float v = rmax[i];
        v = fmaxf(v, __shfl_xor(v, 1));
        v = fmaxf(v, __shfl_xor(v, 2));
        v = fmaxf(v, __shfl_xor(v, 4));
        v = fmaxf(v, __shfl_xor(v, 8));
        rmax[i] = v;
    }
    if (l16 == 0) {
#pragma unroll
        for (int rf = 0; rf < 2; rf++)
#pragma unroll
            for (int r = 0; r < 4; r++)
                red2[i0 + rf * 16 + gp * 4 + r] = rmax[rf * 4 + r];
    }
    __syncthreads();

    // ---- tanh + softmax over the 256 row-maxima ----
    float x = -1e30f;
    if (tid < 256) x = tanhf(red2[tid]);
    float mx = x;
#pragma unroll
    for (int s = 1; s < 64; s <<= 1) mx = fmaxf(mx, __shfl_xor(mx, s));
    if (ln == 0) scratch[wid] = mx;
    __syncthreads();
    float bm = scratch[0];
#pragma unroll
    for (int i = 1; i < 8; i++) bm = fmaxf(bm, scratch[i]);
    float e = (tid < 256) ? expf(x - bm) : 0.f;
    float sm = e;
#pragma unroll
    for (int s = 1; s < 64; s <<= 1) sm += __shfl_xor(sm, s);
    if (ln == 0) scratch[8 + wid] = sm;
    __syncthreads();
    float tot = 0.f;
#pragma unroll
    for (int i = 0; i < 8; i++) tot += scratch[8 + i];
    if (tid < 256) red2[tid] = e / tot;    // aq
    __syncthreads();

    // ---- f_w[d] = sum_l aq[l] * E_b[l][d]  (E from LDS, partials in fred, bank-swizzled) ----
    {
        int g = tid >> 5;                    // 0..15 -> l-range [16g, 16g+16)
        int d0 = (tid & 31) << 3;            // 8 d's per thread
        float s0[8] = {0.f, 0.f, 0.f, 0.f, 0.f, 0.f, 0.f, 0.f};
        int lbase = g << 4;
#pragma unroll
        for (int li = 0; li < 16; li++) {
            int l = lbase + li;
            float aql = red2[l];
            int byt = (l << 9) | ((d0 * 2) ^ ((l & 15) << 4));
            short8 v = *(const short8*)(EsC + byt);
#pragma unroll
            for (int jj = 0; jj < 8; jj++)
                s0[jj] += aql * bf2f((unsigned short)v[jj]);
        }
        f32x4 w0, w1;
        w0[0] = s0[0]; w0[1] = s0[1]; w0[2] = s0[2]; w0[3] = s0[3];
        w1[0] = s0[4]; w1[1] = s0[5]; w1[2] = s0[6]; w1[3] = s0[7];
        *(f32x4*)(fred + g * 256 + fsw(d0)) = w0;
        *(f32x4*)(fred + g * 256 + fsw(d0 + 4)) = w1;
    }
    __syncthreads();
    if (tid < 256) {
        float f = 0.f;
        int dw = fsw(tid);
#pragma unroll
        for (int g2 = 0; g2 < 16; g2++) f += fred[g2 * 256 + dw];
        fw[(b << 8) + tid] = f;
    }
}

// ---------------- Kernel 3: out = f_w @ lin_w^T + lin_b ----------------
// Single-stage LDS (1 barrier): BsT[k][n] transposed (float4 n-reads), As[m][k].
// Tile 32(M)x64(N), 256 blocks.  (r14-r19 proven: ~1us)
__global__ __launch_bounds__(256) void k_out(const float* __restrict__ fw,
                                             const float* __restrict__ lw,
                                             const float* __restrict__ lb,
                                             float* __restrict__ out) {
    __shared__ float BsT[256][68];   // [k][n]
    __shared__ float As[32][260];    // [m][k]
    int tid = threadIdx.x;
    int tx = tid & 15, ty = tid >> 4;
    int r0 = blockIdx.y * 32, n0 = blockIdx.x * 64;
#pragma unroll
    for (int it = 0; it < 8; it++) {
        int f4 = it * 256 + tid;
        int i = f4 >> 6, kc = (f4 & 63) << 2;
        *(float4*)&As[i][kc] = *(const float4*)&fw[(r0 + i) * 256 + kc];
    }
#pragma unroll
    for (int it = 0; it < 16; it++) {
        int f4 = it * 256 + tid;
        int n = f4 >> 6, kc = (f4 & 63) << 2;
        int nn = n0 + n;
        float4 v = {0.f, 0.f, 0.f, 0.f};
        if (nn < O_) v = *(const float4*)&lw[(size_t)nn * 256 + kc];
        BsT[kc][n] = v.x; BsT[kc + 1][n] = v.y; BsT[kc + 2][n] = v.z; BsT[kc + 3][n] = v.w;
    }
    __syncthreads();
    float acc[2][4] = {};
#pragma unroll 4
    for (int k = 0; k < 256; k++) {
        float4 bv = *(const float4*)&BsT[k][tx * 4];
        float a0 = As[ty * 2][k], a1 = As[ty * 2 + 1][k];
        acc[0][0] += a0 * bv.x; acc[0][1] += a0 * bv.y; acc[0][2] += a0 * bv.z; acc[0][3] += a0 * bv.w;
        acc[1][0] += a1 * bv.x; acc[1][1] += a1 * bv.y; acc[1][2] += a1 * bv.z; acc[1][3] += a1 * bv.w;
    }
#pragma unroll
    for (int i = 0; i < 2; i++)
#pragma unroll
        for (int j = 0; j < 4; j++) {
            int n = n0 + tx * 4 + j;
            if (n < O_) out[(size_t)(r0 + ty * 2 + i) * O_ + n] = acc[i][j] + lb[n];
        }
}

extern "C" void kernel_launch(void* const* d_in, const int* in_sizes, int n_in,
                              void* d_out, int out_size, void* d_ws, size_t ws_size,
                              hipStream_t stream) {
    const int* tok = (const int*)d_in[0];
    const float* emb = (const float*)d_in[1];
    const float* Wb = (const float*)d_in[2];
    const float* lw = (const float*)d_in[3];
    const float* lb = (const float*)d_in[4];
    float* out = (float*)d_out;

    char* ws = (char*)d_ws;
    unsigned short* Wbf = (unsigned short*)(ws);            // 131,072 B
    float*          fwp = (float*)(ws + 131072);            // 524,288 B

    hipLaunchKernelGGL(k_wt,   dim3(256),    dim3(256), 0, stream, Wb, Wbf);
    hipLaunchKernelGGL(k_attn, dim3(512),    dim3(512), 0, stream, tok, emb, Wbf, fwp);
    hipLaunchKernelGGL(k_out,  dim3(16, 16), dim3(256), 0, stream, fwp, lw, lb, out);
}